// Round 4
// baseline (68.119 us; speedup 1.0000x reference)
//
#include <hip/hip_runtime.h>
#include <math.h>

// QPU layer: quaternion power + chained Hamilton product + normalize.
// x: (P, 4*C_IN) as [r|i|j|k], weight: (C_OUT, C_IN), bias: (C_OUT)
// out: (P, 4*C_OUT) as [r|i|j|k]
//
// Round 4: packed polynomial sincos. |theta| = |w*theta0 + b| <= 0.733 rad
// (Xavier bound), so degree-7 sin / degree-8 cos Taylor gives ~2e-7 error.
// All main-loop math is <2 x float> -> v_pk_fma_f32 / v_pk_mul_f32.

typedef float v2f __attribute__((ext_vector_type(2)));

#define C_IN   64
#define C_OUT  128
#define POS_PER_BLOCK 4
#define BLOCK  (POS_PER_BLOCK * 64)      // 256 threads = 4 waves, 1 wave/position
#define WSTR2  (C_OUT / 2 + 1)           // float2 row stride 65 (odd -> no pow2 bank stride)

__global__ __launch_bounds__(BLOCK, 2) void qpu_kernel(
    const float* __restrict__ x,
    const float* __restrict__ weight,
    const float* __restrict__ bias,
    float* __restrict__ out,
    int P)
{
    // weight transposed, float2 elements: w2[c*WSTR2 + l] = {W[2l][c], W[2l+1][c]}
    __shared__ float  w_s[C_IN * WSTR2 * 2];          // ~33.3 KB
    __shared__ float4 pre[POS_PER_BLOCK][C_IN];       // (theta0, i/n, j/n, k/n)  4 KB

    const int tid  = threadIdx.x;
    const int lane = tid & 63;
    const int sub  = tid >> 6;           // wave id == position within block

    // ---- stage weight transposed into LDS (float4 global loads) ----
    {
        const float4* w4 = (const float4*)weight;
        #pragma unroll
        for (int idx = tid; idx < (C_OUT * C_IN) / 4; idx += BLOCK) {
            const float4 v = w4[idx];
            const int o  = idx >> 4;
            const int c0 = (idx & 15) * 4;
            w_s[(c0 + 0) * (2 * WSTR2) + o] = v.x;
            w_s[(c0 + 1) * (2 * WSTR2) + o] = v.y;
            w_s[(c0 + 2) * (2 * WSTR2) + o] = v.z;
            w_s[(c0 + 3) * (2 * WSTR2) + o] = v.w;
        }
    }

    const int pos = blockIdx.x * POS_PER_BLOCK + sub;
    const bool valid = (pos < P);

    // ---- per-position preprocessing: 64 lanes, one channel each ----
    if (valid) {
        const int c = lane;
        const float* xb = x + (size_t)pos * (4 * C_IN);
        const float r = xb[c];
        const float i = xb[C_IN + c];
        const float j = xb[2 * C_IN + c];
        const float k = xb[3 * C_IN + c];
        const float rc = fminf(fmaxf(r, -0.999999f), 0.999999f);   // CLAMP = 1-1e-6
        const float th0 = acosf(rc);
        const float inv = rsqrtf(fmaf(i, i, fmaf(j, j, fmaf(k, k, 1e-12f))));
        pre[sub][c] = make_float4(th0, i * inv, j * inv, k * inv);
    }
    __syncthreads();

    if (!valid) return;

    const v2f b2 = ((const v2f*)bias)[lane];
    const v2f* __restrict__ w2 = (const v2f*)w_s;

    // Taylor coefficients (|x| <= 0.74 rad: sin err ~1.7e-7, cos err ~1.2e-8)
    const float S1 = -1.6666667e-1f, S2 = 8.3333333e-3f, S3 = -1.9841270e-4f;
    const float C1 = -0.5f, C2 = 4.1666667e-2f, C3 = -1.3888889e-3f, C4 = 2.4801587e-5f;

    // two packed left-fold Hamilton chains
    v2f pr = 1.0f, pi = 0.0f, pj = 0.0f, pk = 0.0f;

    #pragma unroll 8
    for (int c = 0; c < C_IN; ++c) {
        const float4 p4 = pre[sub][c];            // wave-uniform addr -> LDS broadcast
        const v2f    w  = w2[c * WSTR2 + lane];   // ds_read_b64, conflict-free
        const v2f    th = w * p4.x + b2;          // v_pk_fma (scalar broadcast)
        const v2f    x2 = th * th;
        // sin(th) = th * (1 + x2*(S1 + x2*(S2 + x2*S3)))
        v2f sp = S2 + x2 * S3;
        sp = S1 + x2 * sp;
        const v2f s = th + th * (x2 * sp);
        // cos(th) = 1 + x2*(C1 + x2*(C2 + x2*(C3 + x2*C4)))
        v2f cp = C3 + x2 * C4;
        cp = C2 + x2 * cp;
        cp = C1 + x2 * cp;
        const v2f ct = 1.0f + x2 * cp;
        const v2f qi = p4.y * s;                  // v_pk_mul
        const v2f qj = p4.z * s;
        const v2f qk = p4.w * s;
        // p = p (x) q  (Hamilton, p on the left) — all packed mul/fma
        const v2f nr = pr * ct - pi * qi - pj * qj - pk * qk;
        const v2f ni = pr * qi + pi * ct + pj * qk - pk * qj;
        const v2f nj = pr * qj - pi * qk + pj * ct + pk * qi;
        const v2f nk = pr * qk + pi * qj - pj * qi + pk * ct;
        pr = nr; pi = ni; pj = nj; pk = nk;
    }

    // packed normalize
    const v2f n2 = pr * pr + pi * pi + pj * pj + pk * pk + 1e-12f;
    v2f invn;
    invn.x = rsqrtf(n2.x);
    invn.y = rsqrtf(n2.y);
    pr *= invn; pi *= invn; pj *= invn; pk *= invn;

    // coalesced float2 stores: lane l covers out channels 2l, 2l+1
    float* ob = out + (size_t)pos * (4 * C_OUT);
    ((v2f*)(ob              ))[lane] = pr;
    ((v2f*)(ob +     C_OUT  ))[lane] = pi;
    ((v2f*)(ob + 2 * C_OUT  ))[lane] = pj;
    ((v2f*)(ob + 3 * C_OUT  ))[lane] = pk;
}

extern "C" void kernel_launch(void* const* d_in, const int* in_sizes, int n_in,
                              void* d_out, int out_size, void* d_ws, size_t ws_size,
                              hipStream_t stream) {
    const float* x      = (const float*)d_in[0];
    const float* weight = (const float*)d_in[1];
    const float* bias   = (const float*)d_in[2];
    float* out          = (float*)d_out;

    const int P = in_sizes[0] / (4 * C_IN);   // B*T = 2048
    const int grid = (P + POS_PER_BLOCK - 1) / POS_PER_BLOCK;

    qpu_kernel<<<grid, BLOCK, 0, stream>>>(x, weight, bias, out, P);
}

// Round 5
// 67.252 us; speedup vs baseline: 1.0129x; 1.0129x over previous
//
#include <hip/hip_runtime.h>
#include <math.h>

// QPU layer: quaternion power + chained Hamilton product + normalize.
// x: (P, 4*C_IN) as [r|i|j|k], weight: (C_OUT, C_IN), bias: (C_OUT)
// out: (P, 4*C_OUT) as [r|i|j|k]
//
// Round 5: split-chain parallelism. The Hamilton fold is associative, so
// each 64-step chain is split into two 32-step half-chains on two waves
// (4096 waves total = 4/SIMD instead of 2), combined via one extra Hamilton
// product through LDS. Main loop = packed fp32 + hw v_sin/v_cos (round-3 form).

typedef float v2f __attribute__((ext_vector_type(2)));

#define C_IN   64
#define C_OUT  128
#define POS_PER_BLOCK 4
#define BLOCK  512                       // 8 waves: wave w -> pos w>>1, half w&1
#define HALF   (C_IN / 2)                // 32 channels per half-chain
#define WSTR2  (C_OUT / 2 + 1)           // float2 row stride 65 (odd -> no pow2 bank stride)

#define INV_2PI 0.15915494309189535f

__global__ __launch_bounds__(BLOCK, 2) void qpu_kernel(
    const float* __restrict__ x,
    const float* __restrict__ weight,
    const float* __restrict__ bias,
    float* __restrict__ out,
    int P)
{
    __shared__ float  w_s[C_IN * WSTR2 * 2];          // transposed weight, ~33.3 KB
    __shared__ float4 pre[POS_PER_BLOCK][C_IN];       // (theta0, i/n, j/n, k/n)  4 KB
    __shared__ v2f    part[POS_PER_BLOCK][4][64];     // half-1 partial quats      4 KB

    const int tid  = threadIdx.x;
    const int lane = tid & 63;
    const int wave = tid >> 6;
    const int sub  = wave >> 1;          // position within block (0..3)
    const int half = wave & 1;           // which half of the chain

    // ---- stage weight transposed into LDS (float4 global loads) ----
    // w_s float index for (c,o): c*130 + o
    {
        const float4* w4 = (const float4*)weight;
        #pragma unroll
        for (int idx = tid; idx < (C_OUT * C_IN) / 4; idx += BLOCK) {
            const float4 v = w4[idx];
            const int o  = idx >> 4;
            const int c0 = (idx & 15) * 4;
            w_s[(c0 + 0) * (2 * WSTR2) + o] = v.x;
            w_s[(c0 + 1) * (2 * WSTR2) + o] = v.y;
            w_s[(c0 + 2) * (2 * WSTR2) + o] = v.z;
            w_s[(c0 + 3) * (2 * WSTR2) + o] = v.w;
        }
    }

    const int pos = blockIdx.x * POS_PER_BLOCK + sub;
    const bool valid = (pos < P);

    // ---- per-position preprocessing: threads t<64 of each 128-thread sub ----
    {
        const int t = tid & 127;
        if (valid && t < C_IN) {
            const int c = t;
            const float* xb = x + (size_t)pos * (4 * C_IN);
            const float r = xb[c];
            const float i = xb[C_IN + c];
            const float j = xb[2 * C_IN + c];
            const float k = xb[3 * C_IN + c];
            const float rc = fminf(fmaxf(r, -0.999999f), 0.999999f);  // CLAMP = 1-1e-6
            const float th0 = acosf(rc);
            const float inv = rsqrtf(fmaf(i, i, fmaf(j, j, fmaf(k, k, 1e-12f))));
            pre[sub][c] = make_float4(th0, i * inv, j * inv, k * inv);
        }
    }
    __syncthreads();

    // bias pair for outputs (2*lane, 2*lane+1), folded to revolution domain
    const v2f b2 = ((const v2f*)bias)[lane] * INV_2PI;
    const v2f* __restrict__ w2 = (const v2f*)w_s;

    // half-chain left fold: c in [half*32, half*32+32)
    v2f pr = 1.0f, pi = 0.0f, pj = 0.0f, pk = 0.0f;

    if (valid) {
        const int c0 = half * HALF;
        #pragma unroll 8
        for (int cc = 0; cc < HALF; ++cc) {
            const int c = c0 + cc;
            const float4 p4 = pre[sub][c];            // wave-uniform -> LDS broadcast
            const v2f    w  = w2[c * WSTR2 + lane];   // ds_read_b64, conflict-free
            const v2f    rev = w * (p4.x * INV_2PI) + b2;  // |rev| < 0.25
            v2f s, ct;
            s.x  = __builtin_amdgcn_sinf(rev.x);      // v_sin_f32: sin(rev*2pi)
            s.y  = __builtin_amdgcn_sinf(rev.y);
            ct.x = __builtin_amdgcn_cosf(rev.x);
            ct.y = __builtin_amdgcn_cosf(rev.y);
            const v2f qi = p4.y * s;
            const v2f qj = p4.z * s;
            const v2f qk = p4.w * s;
            // p = p (x) q  (Hamilton, p on the left)
            const v2f nr = pr * ct - pi * qi - pj * qj - pk * qk;
            const v2f ni = pr * qi + pi * ct + pj * qk - pk * qj;
            const v2f nj = pr * qj - pi * qk + pj * ct + pk * qi;
            const v2f nk = pr * qk + pi * qj - pj * qi + pk * ct;
            pr = nr; pi = ni; pj = nj; pk = nk;
        }
    }

    // half-1 waves publish partials
    if (half == 1) {
        part[sub][0][lane] = pr;
        part[sub][1][lane] = pi;
        part[sub][2][lane] = pj;
        part[sub][3][lane] = pk;
    }
    __syncthreads();

    if (!valid || half == 1) return;

    // combine: total = A (x) B  (A = first half, local; B = second half, LDS)
    const v2f Br = part[sub][0][lane];
    const v2f Bi = part[sub][1][lane];
    const v2f Bj = part[sub][2][lane];
    const v2f Bk = part[sub][3][lane];
    const v2f tr = pr * Br - pi * Bi - pj * Bj - pk * Bk;
    const v2f ti = pr * Bi + pi * Br + pj * Bk - pk * Bj;
    const v2f tj = pr * Bj - pi * Bk + pj * Br + pk * Bi;
    const v2f tk = pr * Bk + pi * Bj - pj * Bi + pk * Br;

    // packed normalize
    const v2f n2 = tr * tr + ti * ti + tj * tj + tk * tk + 1e-12f;
    v2f invn;
    invn.x = rsqrtf(n2.x);
    invn.y = rsqrtf(n2.y);

    // coalesced float2 stores: lane l covers out channels 2l, 2l+1
    float* ob = out + (size_t)pos * (4 * C_OUT);
    ((v2f*)(ob            ))[lane] = tr * invn;
    ((v2f*)(ob +     C_OUT))[lane] = ti * invn;
    ((v2f*)(ob + 2 * C_OUT))[lane] = tj * invn;
    ((v2f*)(ob + 3 * C_OUT))[lane] = tk * invn;
}

extern "C" void kernel_launch(void* const* d_in, const int* in_sizes, int n_in,
                              void* d_out, int out_size, void* d_ws, size_t ws_size,
                              hipStream_t stream) {
    const float* x      = (const float*)d_in[0];
    const float* weight = (const float*)d_in[1];
    const float* bias   = (const float*)d_in[2];
    float* out          = (float*)d_out;

    const int P = in_sizes[0] / (4 * C_IN);   // B*T = 2048
    const int grid = (P + POS_PER_BLOCK - 1) / POS_PER_BLOCK;

    qpu_kernel<<<grid, BLOCK, 0, stream>>>(x, weight, bias, out, P);
}